// Round 10
// baseline (224.158 us; speedup 1.0000x reference)
//
#include <hip/hip_runtime.h>
#include <cstdint>
#include <cstddef>

// Problem: x += ssm_scan(rmsnorm(x,s1)); out = x + gelu(rmsnorm(x,s2)@w1+b1)@w2+b2
// B=4 L=2048 D=1024 N=16 DFF=4096, f32 in/out. bf16 MFMA GEMMs, 16 waves/block.

#define BATCH 4
#define SEQLEN 2048
#define DMODEL 1024
#define NSTATE 16
#define DFF 4096
#define NCH 32     // chunks over L
#define LCH 64     // SEQLEN / NCH

typedef unsigned short ushort_t;
typedef __attribute__((ext_vector_type(8))) short short8;
typedef __attribute__((ext_vector_type(4))) float f32x4;

__device__ __forceinline__ ushort_t f2bf(float f) {
  uint32_t u = __builtin_bit_cast(uint32_t, f);
  uint32_t r = (u + 0x7FFFu + ((u >> 16) & 1u)) >> 16;
  return (ushort_t)r;
}

// ---------------- coefficient precompute ----------------
__global__ void coef_kernel(const float* __restrict__ A_ssm, const float* __restrict__ B_ssm,
                            const float* __restrict__ C_ssm,
                            float* __restrict__ dA_t, float* __restrict__ dBz_t,
                            float* __restrict__ dAc_t, float* __restrict__ Ct) {
  int d = blockIdx.x * 256 + threadIdx.x;
  if (d >= DMODEL) return;
  const float l0 = -6.907755278982137f;       // log(0.001)
  const float ld = 0.30701134573253947f;      // log(100)/15
  for (int n = 0; n < NSTATE; n++) {
    float dt = expf(l0 + (float)n * ld);
    float a  = A_ssm[d * NSTATE + n];
    float ea = expf(a);
    float da = expf(-ea * dt);
    float dbz = B_ssm[d * NSTATE + n] * (1.f - da) / ea;
    float dac = expf(-ea * dt * (float)LCH);
    dA_t [n * DMODEL + d] = da;
    dBz_t[n * DMODEL + d] = dbz;
    dAc_t[n * DMODEL + d] = dac;
    Ct   [n * DMODEL + d] = C_ssm[d * NSTATE + n];
  }
}

// ---------------- transpose f32 [R][C] -> bf16 [C][R] ----------------
__global__ void transpose_to_bf16(const float* __restrict__ src, ushort_t* __restrict__ dst,
                                  int R, int C) {
  __shared__ float tile[32][33];
  int bx = blockIdx.x * 32, by = blockIdx.y * 32;
  int tx = threadIdx.x, ty = threadIdx.y;
  #pragma unroll
  for (int i = 0; i < 4; i++) {
    int r = by + ty + i * 8;
    tile[ty + i * 8][tx] = src[(size_t)r * C + bx + tx];
  }
  __syncthreads();
  #pragma unroll
  for (int i = 0; i < 4; i++) {
    int c = bx + ty + i * 8;
    dst[(size_t)c * R + by + tx] = f2bf(tile[tx][ty + i * 8]);
  }
}

// ---------------- rmsnorm pass 1: rrms per row ----------------
__global__ void rms1_kernel(const float* __restrict__ x, float* __restrict__ rrms) {
  int row = blockIdx.x * 4 + (threadIdx.x >> 6);
  int lane = threadIdx.x & 63;
  const float4* p = (const float4*)(x + (size_t)row * DMODEL);
  float s = 0.f;
  #pragma unroll
  for (int w = 0; w < 4; w++) {
    float4 v = p[w * 64 + lane];
    s += v.x * v.x + v.y * v.y + v.z * v.z + v.w * v.w;
  }
  #pragma unroll
  for (int off = 32; off; off >>= 1) s += __shfl_xor(s, off, 64);
  if (lane == 0) rrms[row] = rsqrtf(s * (1.f / DMODEL) + 1e-6f);
}

// ---------------- scan pass1: per-chunk local final states ----------------
__global__ void scan_pass1(const float* __restrict__ x, const float* __restrict__ rrms,
                           const float* __restrict__ scale1,
                           const float* __restrict__ dA_t, const float* __restrict__ dBz_t,
                           float* __restrict__ s_fin) {
  int d = blockIdx.x * 256 + threadIdx.x;
  int b = blockIdx.y, c = blockIdx.z;
  float dA[NSTATE], dBz[NSTATE], s[NSTATE];
  #pragma unroll
  for (int n = 0; n < NSTATE; n++) {
    dA[n] = dA_t[n * DMODEL + d];
    dBz[n] = dBz_t[n * DMODEL + d];
    s[n] = 0.f;
  }
  float sc1 = scale1[d];
  const float* xp = x + ((size_t)b * SEQLEN + (size_t)c * LCH) * DMODEL + d;
  const float* rp = rrms + b * SEQLEN + c * LCH;
  for (int t = 0; t < LCH; t++) {
    float u = xp[(size_t)t * DMODEL] * rp[t] * sc1;
    #pragma unroll
    for (int n = 0; n < NSTATE; n++) s[n] = fmaf(s[n], dA[n], u * dBz[n]);
  }
  #pragma unroll
  for (int n = 0; n < NSTATE; n++)
    s_fin[(((size_t)n * BATCH + b) * NCH + c) * DMODEL + d] = s[n];
}

// ---------------- scan pass2: serial chunk-carry combine ----------------
__global__ void scan_pass2(const float* __restrict__ s_fin, const float* __restrict__ dAc_t,
                           float* __restrict__ s_in) {
  int idx = blockIdx.x * 256 + threadIdx.x;  // BATCH*DMODEL*NSTATE = 65536
  int d = idx & (DMODEL - 1);
  int b = (idx >> 10) & (BATCH - 1);
  int n = idx >> 12;
  float dc = dAc_t[n * DMODEL + d];
  float s = 0.f;
  for (int c = 0; c < NCH; c++) {
    size_t o = (((size_t)n * BATCH + b) * NCH + c) * DMODEL + d;
    s_in[o] = s;
    s = s_fin[o] + dc * s;
  }
}

// ---------------- scan pass3: full scan with carry-in, write x2 = x + y + u*D ----------------
__global__ void scan_pass3(const float* __restrict__ x, const float* __restrict__ rrms,
                           const float* __restrict__ scale1,
                           const float* __restrict__ dA_t, const float* __restrict__ dBz_t,
                           const float* __restrict__ Ct, const float* __restrict__ Dv,
                           const float* __restrict__ s_in, float* __restrict__ out) {
  int d = blockIdx.x * 256 + threadIdx.x;
  int b = blockIdx.y, c = blockIdx.z;
  float dA[NSTATE], dBz[NSTATE], Cc[NSTATE], s[NSTATE];
  #pragma unroll
  for (int n = 0; n < NSTATE; n++) {
    dA[n] = dA_t[n * DMODEL + d];
    dBz[n] = dBz_t[n * DMODEL + d];
    Cc[n] = Ct[n * DMODEL + d];
    s[n] = s_in[(((size_t)n * BATCH + b) * NCH + c) * DMODEL + d];
  }
  float sc1 = scale1[d], Dd = Dv[d];
  const float* xp = x + ((size_t)b * SEQLEN + (size_t)c * LCH) * DMODEL + d;
  const float* rp = rrms + b * SEQLEN + c * LCH;
  float* op = out + ((size_t)b * SEQLEN + (size_t)c * LCH) * DMODEL + d;
  for (int t = 0; t < LCH; t++) {
    float xv = xp[(size_t)t * DMODEL];
    float u = xv * rp[t] * sc1;
    float y = 0.f;
    #pragma unroll
    for (int n = 0; n < NSTATE; n++) {
      s[n] = fmaf(s[n], dA[n], u * dBz[n]);
      y = fmaf(Cc[n], s[n], y);
    }
    op[(size_t)t * DMODEL] = xv + y + u * Dd;
  }
}

// ---------------- rmsnorm2: x2 -> bf16 normalized ----------------
__global__ void rms2_kernel(const float* __restrict__ x2, const float* __restrict__ scale2,
                            ushort_t* __restrict__ hb) {
  int row = blockIdx.x * 4 + (threadIdx.x >> 6);
  int lane = threadIdx.x & 63;
  const float4* p = (const float4*)(x2 + (size_t)row * DMODEL);
  float4 v[4];
  float s = 0.f;
  #pragma unroll
  for (int w = 0; w < 4; w++) {
    v[w] = p[w * 64 + lane];
    s += v[w].x * v[w].x + v[w].y * v[w].y + v[w].z * v[w].z + v[w].w * v[w].w;
  }
  #pragma unroll
  for (int off = 32; off; off >>= 1) s += __shfl_xor(s, off, 64);
  float r = rsqrtf(s * (1.f / DMODEL) + 1e-6f);
  const float4* sc = (const float4*)scale2;
  #pragma unroll
  for (int w = 0; w < 4; w++) {
    float4 scv = sc[w * 64 + lane];
    ushort4 u;
    u.x = f2bf(v[w].x * r * scv.x);
    u.y = f2bf(v[w].y * r * scv.y);
    u.z = f2bf(v[w].z * r * scv.z);
    u.w = f2bf(v[w].w * r * scv.w);
    *(ushort4*)(hb + (size_t)row * DMODEL + (size_t)(w * 64 + lane) * 4) = u;
  }
}

// ========== unified 16-wave GEMM (r9 gemm16_2 structure — the near-floor one) ==========
// C[M][N] = A[M][K]*B[N][K]^T. 256x128 tile, BK=64, 3-slot (144 KB), 1024 threads,
// wave tile 64x32. Per tile: {12 ds_read_b128; stage(t+2, 3 gl2lds/thread uniform);
// setprio; 16 MFMA; setprio; fence vmcnt(3); s_barrier}. Prologue fence+bar (r4 lesson).
// Swizzle: linear LDS dest + pre-swizzled global src col + XOR'd read col (0 conflicts).

template <int N>
__device__ __forceinline__ void fence_vm() {
  asm volatile("s_waitcnt vmcnt(%0)" :: "n"(N) : "memory");
}

__device__ __forceinline__ void bar() { asm volatile("s_barrier" ::: "memory"); }

__device__ __forceinline__ void gl2lds16(const ushort_t* g, ushort_t* l) {
  __builtin_amdgcn_global_load_lds(
      (const __attribute__((address_space(1))) unsigned int*)g,
      (__attribute__((address_space(3))) unsigned int*)l, 16, 0, 0);
}

// MODE 1: out = bf16(gelu_sigmoid(acc + bias));  MODE 2: out = resid + acc + bias (f32)
template <int K, int MODE>
__global__ __launch_bounds__(1024, 4) void gemm16u(const ushort_t* __restrict__ A,
                                                   const ushort_t* __restrict__ B,
                                                   const float* __restrict__ bias,
                                                   const float* __restrict__ resid,
                                                   void* __restrict__ outp,
                                                   int M, int N) {
  constexpr int TILEA = 16384;              // A: 256x64 elems
  constexpr int SLOT  = TILEA + 8192;       // + B: 128x64
  constexpr int NT = K / 64;
  __shared__ __align__(16) ushort_t lds[3 * SLOT];   // 144 KB

  const int tid = threadIdx.x;
  const int wave = tid >> 6, lane = tid & 63;
  const int wr = wave >> 2, wc = wave & 3;

  const int nwg = gridDim.x, cpx = nwg >> 3, bid = blockIdx.x;
  const int wg = (bid & 7) * cpx + (bid >> 3);
  const int nbn = N / 128;
  const int m0 = (wg / nbn) * 256, n0 = (wg % nbn) * 128;

  // staging: row = tid>>3 (0..127 per piece), chunk = tid&7; BK=64 (128B-row) swizzle
  const int scol = 8 * ((tid & 7) ^ ((tid >> 3) & 7));
  const ushort_t* aB = A + (size_t)(m0 + (tid >> 3)) * K + scol;   // A rows 0-127 (+128)
  const ushort_t* bB = B + (size_t)(n0 + (tid >> 3)) * K + scol;   // B rows 0-127
  const int wo = wave * 512;

  auto stage = [&](int slot, int t) {       // 3 loads/thread, uniform across waves
    ushort_t* sA = lds + slot * SLOT;
    gl2lds16(aB + (size_t)t * 64, sA + wo);
    gl2lds16(aB + (size_t)128 * K + (size_t)t * 64, sA + 8192 + wo);
    gl2lds16(bB + (size_t)t * 64, sA + TILEA + wo);
  };

  f32x4 acc[4][2] = {};

  stage(0, 0); stage(1, 1);
  fence_vm<3>(); bar();                     // tile 0 landed, tile 1 in flight

  const int rl = lane & 15, c4 = lane >> 4;
  const int sw0 = (c4 ^ (rl & 7)) * 8;           // kk=0 read swizzle (BK=64 pattern)
  const int sw1 = ((4 | c4) ^ (rl & 7)) * 8;     // kk=1

  int s0 = 0;
  for (int t = 0; t < NT; ++t) {
    const ushort_t* sA = lds + s0 * SLOT;
    const ushort_t* sB = sA + TILEA;

    short8 af[2][4], bf[2][2];
    #pragma unroll
    for (int m = 0; m < 4; m++) {
      const ushort_t* p = sA + (size_t)(wr * 64 + m * 16 + rl) * 64;
      af[0][m] = *(const short8*)(p + sw0);
      af[1][m] = *(const short8*)(p + sw1);
    }
    #pragma unroll
    for (int n = 0; n < 2; n++) {
      const ushort_t* p = sB + (size_t)(wc * 32 + n * 16 + rl) * 64;
      bf[0][n] = *(const short8*)(p + sw0);
      bf[1][n] = *(const short8*)(p + sw1);
    }

    if (t + 2 < NT) {
      int s2 = s0 + 2; if (s2 >= 3) s2 -= 3;
      stage(s2, t + 2);
    }

    __builtin_amdgcn_s_setprio(1);
    #pragma unroll
    for (int kk = 0; kk < 2; kk++)
      #pragma unroll
      for (int m = 0; m < 4; m++)
        #pragma unroll
        for (int n = 0; n < 2; n++)
          acc[m][n] = __builtin_amdgcn_mfma_f32_16x16x32_bf16(af[kk][m], bf[kk][n],
                                                              acc[m][n], 0, 0, 0);
    __builtin_amdgcn_s_setprio(0);

    if (t + 2 < NT) fence_vm<3>();          // tile t+1 landed; t+2 in flight
    else            fence_vm<0>();
    bar();

    s0 = (s0 == 2) ? 0 : s0 + 1;
  }

  // epilogue
  const int colb = n0 + wc * 32 + rl;
  const int rowb = m0 + wr * 64 + c4 * 4;
  #pragma unroll
  for (int n = 0; n < 2; n++) {
    int col = colb + n * 16;
    float bs = bias[col];
    #pragma unroll
    for (int m = 0; m < 4; m++) {
      int row = rowb + m * 16;
      #pragma unroll
      for (int j = 0; j < 4; j++) {
        float v = acc[m][n][j] + bs;
        size_t o = (size_t)(row + j) * N + col;
        if (MODE == 1) {
          float g = v / (1.f + __expf(-1.702f * v));   // gelu sigmoid approx
          ((ushort_t*)outp)[o] = f2bf(g);
        } else {
          ((float*)outp)[o] = resid[o] + v;
        }
      }
    }
  }
}

// ---------------- launch ----------------
extern "C" void kernel_launch(void* const* d_in, const int* in_sizes, int n_in,
                              void* d_out, int out_size, void* d_ws, size_t ws_size,
                              hipStream_t stream) {
  (void)in_sizes; (void)n_in; (void)out_size; (void)ws_size;
  const float* x      = (const float*)d_in[0];
  const float* A_ssm  = (const float*)d_in[1];
  const float* B_ssm  = (const float*)d_in[2];
  const float* C_ssm  = (const float*)d_in[3];
  const float* D_ssm  = (const float*)d_in[4];
  const float* scale1 = (const float*)d_in[5];
  const float* scale2 = (const float*)d_in[6];
  const float* w1     = (const float*)d_in[7];
  const float* b1     = (const float*)d_in[8];
  const float* w2     = (const float*)d_in[9];
  const float* b2     = (const float*)d_in[10];
  float* out = (float*)d_out;

  char* ws = (char*)d_ws;
  float*    rrms  = (float*)(ws + 0);                         // 32 KB
  float*    dA_t  = (float*)(ws + 32768);                     // 64 KB
  float*    dBz_t = (float*)(ws + 98304);                     // 64 KB
  float*    dAc_t = (float*)(ws + 163840);                    // 64 KB
  float*    Ct    = (float*)(ws + 229376);                    // 64 KB
  float*    s_fin = (float*)(ws + 294912);                    // 8 MB
  float*    s_in  = (float*)(ws + 8683520);                   // 8 MB
  ushort_t* hb    = (ushort_t*)(ws + 17072128);               // 16 MB
  ushort_t* w1t   = (ushort_t*)(ws + 33849344);               // 8 MB
  ushort_t* w2t   = (ushort_t*)(ws + 42237952);               // 8 MB
  ushort_t* gb    = (ushort_t*)(ws + 50626560);               // 64 MB

  const int ROWS = BATCH * SEQLEN;  // 8192

  coef_kernel<<<DMODEL / 256, 256, 0, stream>>>(A_ssm, B_ssm, C_ssm, dA_t, dBz_t, dAc_t, Ct);
  transpose_to_bf16<<<dim3(DFF / 32, DMODEL / 32), dim3(32, 8), 0, stream>>>(w1, w1t, DMODEL, DFF);
  transpose_to_bf16<<<dim3(DMODEL / 32, DFF / 32), dim3(32, 8), 0, stream>>>(w2, w2t, DFF, DMODEL);
  rms1_kernel<<<ROWS / 4, 256, 0, stream>>>(x, rrms);
  scan_pass1<<<dim3(DMODEL / 256, BATCH, NCH), 256, 0, stream>>>(x, rrms, scale1, dA_t, dBz_t, s_fin);
  scan_pass2<<<(BATCH * DMODEL * NSTATE) / 256, 256, 0, stream>>>(s_fin, dAc_t, s_in);
  scan_pass3<<<dim3(DMODEL / 256, BATCH, NCH), 256, 0, stream>>>(x, rrms, scale1, dA_t, dBz_t, Ct,
                                                                 D_ssm, s_in, out);
  rms2_kernel<<<ROWS / 4, 256, 0, stream>>>(out, scale2, hb);

  // gemm1: [8192x1024]@[1024x4096] -> gelu -> gb (bf16). 1024 blocks, 256x128, BK=64.
  gemm16u<DMODEL, 1><<<(ROWS / 256) * (DFF / 128), 1024, 0, stream>>>(
      hb, w1t, b1, nullptr, gb, ROWS, DFF);
  // gemm2: [8192x4096]@[4096x1024] + resid -> out (f32). 256 blocks, 256x128, BK=64.
  gemm16u<DFF, 2><<<(ROWS / 256) * (DMODEL / 128), 1024, 0, stream>>>(
      gb, w2t, b2, out, out, ROWS, DMODEL);
}

// Round 11
// 224.003 us; speedup vs baseline: 1.0007x; 1.0007x over previous
//
#include <hip/hip_runtime.h>
#include <cstdint>
#include <cstddef>

// Problem: x += ssm_scan(rmsnorm(x,s1)); out = x + gelu(rmsnorm(x,s2)@w1+b1)@w2+b2
// B=4 L=2048 D=1024 N=16 DFF=4096, f32 in/out. bf16 MFMA GEMMs, 16 waves/block.

#define BATCH 4
#define SEQLEN 2048
#define DMODEL 1024
#define NSTATE 16
#define DFF 4096
#define NCH 32     // chunks over L
#define LCH 64     // SEQLEN / NCH

typedef unsigned short ushort_t;
typedef __attribute__((ext_vector_type(8))) short short8;
typedef __attribute__((ext_vector_type(4))) float f32x4;

__device__ __forceinline__ ushort_t f2bf(float f) {
  uint32_t u = __builtin_bit_cast(uint32_t, f);
  uint32_t r = (u + 0x7FFFu + ((u >> 16) & 1u)) >> 16;
  return (ushort_t)r;
}

// ---------------- coefficient precompute ----------------
__global__ void coef_kernel(const float* __restrict__ A_ssm, const float* __restrict__ B_ssm,
                            const float* __restrict__ C_ssm,
                            float* __restrict__ dA_t, float* __restrict__ dBz_t,
                            float* __restrict__ dAc_t, float* __restrict__ Ct) {
  int d = blockIdx.x * 256 + threadIdx.x;
  if (d >= DMODEL) return;
  const float l0 = -6.907755278982137f;       // log(0.001)
  const float ld = 0.30701134573253947f;      // log(100)/15
  for (int n = 0; n < NSTATE; n++) {
    float dt = expf(l0 + (float)n * ld);
    float a  = A_ssm[d * NSTATE + n];
    float ea = expf(a);
    float da = expf(-ea * dt);
    float dbz = B_ssm[d * NSTATE + n] * (1.f - da) / ea;
    float dac = expf(-ea * dt * (float)LCH);
    dA_t [n * DMODEL + d] = da;
    dBz_t[n * DMODEL + d] = dbz;
    dAc_t[n * DMODEL + d] = dac;
    Ct   [n * DMODEL + d] = C_ssm[d * NSTATE + n];
  }
}

// ---------------- transpose f32 [R][C] -> bf16 [C][R] ----------------
__global__ void transpose_to_bf16(const float* __restrict__ src, ushort_t* __restrict__ dst,
                                  int R, int C) {
  __shared__ float tile[32][33];
  int bx = blockIdx.x * 32, by = blockIdx.y * 32;
  int tx = threadIdx.x, ty = threadIdx.y;
  #pragma unroll
  for (int i = 0; i < 4; i++) {
    int r = by + ty + i * 8;
    tile[ty + i * 8][tx] = src[(size_t)r * C + bx + tx];
  }
  __syncthreads();
  #pragma unroll
  for (int i = 0; i < 4; i++) {
    int c = bx + ty + i * 8;
    dst[(size_t)c * R + by + tx] = f2bf(tile[tx][ty + i * 8]);
  }
}

// ---------------- rmsnorm pass 1: rrms per row ----------------
__global__ void rms1_kernel(const float* __restrict__ x, float* __restrict__ rrms) {
  int row = blockIdx.x * 4 + (threadIdx.x >> 6);
  int lane = threadIdx.x & 63;
  const float4* p = (const float4*)(x + (size_t)row * DMODEL);
  float s = 0.f;
  #pragma unroll
  for (int w = 0; w < 4; w++) {
    float4 v = p[w * 64 + lane];
    s += v.x * v.x + v.y * v.y + v.z * v.z + v.w * v.w;
  }
  #pragma unroll
  for (int off = 32; off; off >>= 1) s += __shfl_xor(s, off, 64);
  if (lane == 0) rrms[row] = rsqrtf(s * (1.f / DMODEL) + 1e-6f);
}

// ---------------- scan pass1: per-chunk local final states ----------------
__global__ void scan_pass1(const float* __restrict__ x, const float* __restrict__ rrms,
                           const float* __restrict__ scale1,
                           const float* __restrict__ dA_t, const float* __restrict__ dBz_t,
                           float* __restrict__ s_fin) {
  int d = blockIdx.x * 256 + threadIdx.x;
  int b = blockIdx.y, c = blockIdx.z;
  float dA[NSTATE], dBz[NSTATE], s[NSTATE];
  #pragma unroll
  for (int n = 0; n < NSTATE; n++) {
    dA[n] = dA_t[n * DMODEL + d];
    dBz[n] = dBz_t[n * DMODEL + d];
    s[n] = 0.f;
  }
  float sc1 = scale1[d];
  const float* xp = x + ((size_t)b * SEQLEN + (size_t)c * LCH) * DMODEL + d;
  const float* rp = rrms + b * SEQLEN + c * LCH;
  for (int t = 0; t < LCH; t++) {
    float u = xp[(size_t)t * DMODEL] * rp[t] * sc1;
    #pragma unroll
    for (int n = 0; n < NSTATE; n++) s[n] = fmaf(s[n], dA[n], u * dBz[n]);
  }
  #pragma unroll
  for (int n = 0; n < NSTATE; n++)
    s_fin[(((size_t)n * BATCH + b) * NCH + c) * DMODEL + d] = s[n];
}

// ---------------- scan pass2: serial chunk-carry combine ----------------
__global__ void scan_pass2(const float* __restrict__ s_fin, const float* __restrict__ dAc_t,
                           float* __restrict__ s_in) {
  int idx = blockIdx.x * 256 + threadIdx.x;  // BATCH*DMODEL*NSTATE = 65536
  int d = idx & (DMODEL - 1);
  int b = (idx >> 10) & (BATCH - 1);
  int n = idx >> 12;
  float dc = dAc_t[n * DMODEL + d];
  float s = 0.f;
  for (int c = 0; c < NCH; c++) {
    size_t o = (((size_t)n * BATCH + b) * NCH + c) * DMODEL + d;
    s_in[o] = s;
    s = s_fin[o] + dc * s;
  }
}

// ---------------- scan pass3: full scan with carry-in, write x2 = x + y + u*D ----------------
__global__ void scan_pass3(const float* __restrict__ x, const float* __restrict__ rrms,
                           const float* __restrict__ scale1,
                           const float* __restrict__ dA_t, const float* __restrict__ dBz_t,
                           const float* __restrict__ Ct, const float* __restrict__ Dv,
                           const float* __restrict__ s_in, float* __restrict__ out) {
  int d = blockIdx.x * 256 + threadIdx.x;
  int b = blockIdx.y, c = blockIdx.z;
  float dA[NSTATE], dBz[NSTATE], Cc[NSTATE], s[NSTATE];
  #pragma unroll
  for (int n = 0; n < NSTATE; n++) {
    dA[n] = dA_t[n * DMODEL + d];
    dBz[n] = dBz_t[n * DMODEL + d];
    Cc[n] = Ct[n * DMODEL + d];
    s[n] = s_in[(((size_t)n * BATCH + b) * NCH + c) * DMODEL + d];
  }
  float sc1 = scale1[d], Dd = Dv[d];
  const float* xp = x + ((size_t)b * SEQLEN + (size_t)c * LCH) * DMODEL + d;
  const float* rp = rrms + b * SEQLEN + c * LCH;
  float* op = out + ((size_t)b * SEQLEN + (size_t)c * LCH) * DMODEL + d;
  for (int t = 0; t < LCH; t++) {
    float xv = xp[(size_t)t * DMODEL];
    float u = xv * rp[t] * sc1;
    float y = 0.f;
    #pragma unroll
    for (int n = 0; n < NSTATE; n++) {
      s[n] = fmaf(s[n], dA[n], u * dBz[n]);
      y = fmaf(Cc[n], s[n], y);
    }
    op[(size_t)t * DMODEL] = xv + y + u * Dd;
  }
}

// ---------------- rmsnorm2: x2 -> bf16 normalized ----------------
__global__ void rms2_kernel(const float* __restrict__ x2, const float* __restrict__ scale2,
                            ushort_t* __restrict__ hb) {
  int row = blockIdx.x * 4 + (threadIdx.x >> 6);
  int lane = threadIdx.x & 63;
  const float4* p = (const float4*)(x2 + (size_t)row * DMODEL);
  float4 v[4];
  float s = 0.f;
  #pragma unroll
  for (int w = 0; w < 4; w++) {
    v[w] = p[w * 64 + lane];
    s += v[w].x * v[w].x + v[w].y * v[w].y + v[w].z * v[w].z + v[w].w * v[w].w;
  }
  #pragma unroll
  for (int off = 32; off; off >>= 1) s += __shfl_xor(s, off, 64);
  float r = rsqrtf(s * (1.f / DMODEL) + 1e-6f);
  const float4* sc = (const float4*)scale2;
  #pragma unroll
  for (int w = 0; w < 4; w++) {
    float4 scv = sc[w * 64 + lane];
    ushort4 u;
    u.x = f2bf(v[w].x * r * scv.x);
    u.y = f2bf(v[w].y * r * scv.y);
    u.z = f2bf(v[w].z * r * scv.z);
    u.w = f2bf(v[w].w * r * scv.w);
    *(ushort4*)(hb + (size_t)row * DMODEL + (size_t)(w * 64 + lane) * 4) = u;
  }
}

// ========== unified 16-wave GEMM, strength-reduced inner loop ==========
// C[M][N] = A[M][K]*B[N][K]^T. 256x128 tile, BK=64, 3-slot (144 KB), 1024 threads,
// wave tile 64x32. Per tile: {4 base-adds; 12 ds_read_b128 @imm offsets; stage(t+2,
// incremental ptrs); setprio; 16 MFMA; setprio; fence vmcnt(3); s_barrier}.
// r10 delta: ALL addressing hoisted — slot rotation is 2 ops, reads are base+imm,
// staging ptrs advance by +=64. (r10: VALUBusy 32% ~= MfmaUtil from runtime-s0 addr calc.)
// Swizzle: linear LDS dest + pre-swizzled global src col + XOR'd read col (0 conflicts).

template <int N>
__device__ __forceinline__ void fence_vm() {
  asm volatile("s_waitcnt vmcnt(%0)" :: "n"(N) : "memory");
}

__device__ __forceinline__ void bar() { asm volatile("s_barrier" ::: "memory"); }

__device__ __forceinline__ void gl2lds16(const ushort_t* g, ushort_t* l) {
  __builtin_amdgcn_global_load_lds(
      (const __attribute__((address_space(1))) unsigned int*)g,
      (__attribute__((address_space(3))) unsigned int*)l, 16, 0, 0);
}

// MODE 1: out = bf16(gelu_sigmoid(acc + bias));  MODE 2: out = resid + acc + bias (f32)
template <int K, int MODE>
__global__ __launch_bounds__(1024, 4) void gemm16v(const ushort_t* __restrict__ A,
                                                   const ushort_t* __restrict__ B,
                                                   const float* __restrict__ bias,
                                                   const float* __restrict__ resid,
                                                   void* __restrict__ outp,
                                                   int M, int N) {
  constexpr int TILEA = 16384;              // A: 256x64 elems
  constexpr int SLOT  = TILEA + 8192;       // + B: 128x64
  constexpr int NT = K / 64;
  __shared__ __align__(16) ushort_t lds[3 * SLOT];   // 144 KB

  const int tid = threadIdx.x;
  const int wave = tid >> 6, lane = tid & 63;
  const int wr = wave >> 2, wc = wave & 3;

  const int nwg = gridDim.x, cpx = nwg >> 3, bid = blockIdx.x;
  const int wg = (bid & 7) * cpx + (bid >> 3);
  const int nbn = N / 128;
  const int m0 = (wg / nbn) * 256, n0 = (wg % nbn) * 128;

  // staging: row = tid>>3 (0..127 per piece), chunk = tid&7; BK=64 (128B-row) swizzle
  const int scol = 8 * ((tid & 7) ^ ((tid >> 3) & 7));
  const int wo = wave * 512;

  // incremental staging pointers (advance += 64 per staged tile)
  const ushort_t* aStgLo = A + (size_t)(m0 + (tid >> 3)) * K + scol;
  const ushort_t* aStgHi = aStgLo + (size_t)128 * K;
  const ushort_t* bStg   = B + (size_t)(n0 + (tid >> 3)) * K + scol;

  f32x4 acc[4][2] = {};

  // prologue: stage tiles 0 (slot 0) and 1 (slot 1)
  {
    ushort_t* s0p = lds;
    gl2lds16(aStgLo, s0p + wo);
    gl2lds16(aStgHi, s0p + 8192 + wo);
    gl2lds16(bStg,   s0p + TILEA + wo);
    ushort_t* s1p = lds + SLOT;
    gl2lds16(aStgLo + 64, s1p + wo);
    gl2lds16(aStgHi + 64, s1p + 8192 + wo);
    gl2lds16(bStg   + 64, s1p + TILEA + wo);
    aStgLo += 128; aStgHi += 128; bStg += 128;   // now at tile 2
  }
  fence_vm<3>(); bar();                     // tile 0 landed, tile 1 in flight

  const int rl = lane & 15, c4 = lane >> 4;
  const int sw0 = (c4 ^ (rl & 7)) * 8;           // kk=0 read swizzle (BK=64 pattern)
  const int sw1 = ((4 | c4) ^ (rl & 7)) * 8;     // kk=1
  const int aOff = (wr * 64 + rl) * 64;          // thread A base (elems)
  const int bOff = TILEA + (wc * 32 + rl) * 64;  // thread B base (elems)

  // rotating slot bases
  const ushort_t* rSlot = lds;              // read slot (tile t)
  ushort_t*       wSlot = lds + 2 * SLOT;   // write slot (tile t+2)

  for (int t = 0; t < NT; ++t) {
    // four read base pointers; all 12 reads are base + compile-time imm offset
    const ushort_t* ra0 = rSlot + aOff + sw0;
    const ushort_t* ra1 = rSlot + aOff + sw1;
    const ushort_t* rb0 = rSlot + bOff + sw0;
    const ushort_t* rb1 = rSlot + bOff + sw1;

    short8 af[2][4], bf[2][2];
    #pragma unroll
    for (int m = 0; m < 4; m++) {
      af[0][m] = *(const short8*)(ra0 + m * 1024);   // imm: m*2048 B
      af[1][m] = *(const short8*)(ra1 + m * 1024);
    }
    #pragma unroll
    for (int n = 0; n < 2; n++) {
      bf[0][n] = *(const short8*)(rb0 + n * 1024);
      bf[1][n] = *(const short8*)(rb1 + n * 1024);
    }

    if (t + 2 < NT) {
      gl2lds16(aStgLo, wSlot + wo);
      gl2lds16(aStgHi, wSlot + 8192 + wo);
      gl2lds16(bStg,   wSlot + TILEA + wo);
      aStgLo += 64; aStgHi += 64; bStg += 64;
    }

    __builtin_amdgcn_s_setprio(1);
    #pragma unroll
    for (int kk = 0; kk < 2; kk++)
      #pragma unroll
      for (int m = 0; m < 4; m++)
        #pragma unroll
        for (int n = 0; n < 2; n++)
          acc[m][n] = __builtin_amdgcn_mfma_f32_16x16x32_bf16(af[kk][m], bf[kk][n],
                                                              acc[m][n], 0, 0, 0);
    __builtin_amdgcn_s_setprio(0);

    if (t + 2 < NT) fence_vm<3>();          // tile t+1 landed; t+2 in flight
    else            fence_vm<0>();
    bar();

    // rotate slots (2 ops each)
    const ushort_t* rn = rSlot + SLOT;
    rSlot = (rn == lds + 3 * SLOT) ? lds : rn;
    ushort_t* wn = wSlot + SLOT;
    wSlot = (wn == lds + 3 * SLOT) ? lds : wn;
  }

  // epilogue
  const int colb = n0 + wc * 32 + rl;
  const int rowb = m0 + wr * 64 + c4 * 4;
  #pragma unroll
  for (int n = 0; n < 2; n++) {
    int col = colb + n * 16;
    float bs = bias[col];
    #pragma unroll
    for (int m = 0; m < 4; m++) {
      int row = rowb + m * 16;
      #pragma unroll
      for (int j = 0; j < 4; j++) {
        float v = acc[m][n][j] + bs;
        size_t o = (size_t)(row + j) * N + col;
        if (MODE == 1) {
          float g = v / (1.f + __expf(-1.702f * v));   // gelu sigmoid approx
          ((ushort_t*)outp)[o] = f2bf(g);
        } else {
          ((float*)outp)[o] = resid[o] + v;
        }
      }
    }
  }
}

// ---------------- launch ----------------
extern "C" void kernel_launch(void* const* d_in, const int* in_sizes, int n_in,
                              void* d_out, int out_size, void* d_ws, size_t ws_size,
                              hipStream_t stream) {
  (void)in_sizes; (void)n_in; (void)out_size; (void)ws_size;
  const float* x      = (const float*)d_in[0];
  const float* A_ssm  = (const float*)d_in[1];
  const float* B_ssm  = (const float*)d_in[2];
  const float* C_ssm  = (const float*)d_in[3];
  const float* D_ssm  = (const float*)d_in[4];
  const float* scale1 = (const float*)d_in[5];
  const float* scale2 = (const float*)d_in[6];
  const float* w1     = (const float*)d_in[7];
  const float* b1     = (const float*)d_in[8];
  const float* w2     = (const float*)d_in[9];
  const float* b2     = (const float*)d_in[10];
  float* out = (float*)d_out;

  char* ws = (char*)d_ws;
  float*    rrms  = (float*)(ws + 0);                         // 32 KB
  float*    dA_t  = (float*)(ws + 32768);                     // 64 KB
  float*    dBz_t = (float*)(ws + 98304);                     // 64 KB
  float*    dAc_t = (float*)(ws + 163840);                    // 64 KB
  float*    Ct    = (float*)(ws + 229376);                    // 64 KB
  float*    s_fin = (float*)(ws + 294912);                    // 8 MB
  float*    s_in  = (float*)(ws + 8683520);                   // 8 MB
  ushort_t* hb    = (ushort_t*)(ws + 17072128);               // 16 MB
  ushort_t* w1t   = (ushort_t*)(ws + 33849344);               // 8 MB
  ushort_t* w2t   = (ushort_t*)(ws + 42237952);               // 8 MB
  ushort_t* gb    = (ushort_t*)(ws + 50626560);               // 64 MB

  const int ROWS = BATCH * SEQLEN;  // 8192

  coef_kernel<<<DMODEL / 256, 256, 0, stream>>>(A_ssm, B_ssm, C_ssm, dA_t, dBz_t, dAc_t, Ct);
  transpose_to_bf16<<<dim3(DFF / 32, DMODEL / 32), dim3(32, 8), 0, stream>>>(w1, w1t, DMODEL, DFF);
  transpose_to_bf16<<<dim3(DMODEL / 32, DFF / 32), dim3(32, 8), 0, stream>>>(w2, w2t, DFF, DMODEL);
  rms1_kernel<<<ROWS / 4, 256, 0, stream>>>(x, rrms);
  scan_pass1<<<dim3(DMODEL / 256, BATCH, NCH), 256, 0, stream>>>(x, rrms, scale1, dA_t, dBz_t, s_fin);
  scan_pass2<<<(BATCH * DMODEL * NSTATE) / 256, 256, 0, stream>>>(s_fin, dAc_t, s_in);
  scan_pass3<<<dim3(DMODEL / 256, BATCH, NCH), 256, 0, stream>>>(x, rrms, scale1, dA_t, dBz_t, Ct,
                                                                 D_ssm, s_in, out);
  rms2_kernel<<<ROWS / 4, 256, 0, stream>>>(out, scale2, hb);

  // gemm1: [8192x1024]@[1024x4096] -> gelu -> gb (bf16). 1024 blocks, 256x128, BK=64.
  gemm16v<DMODEL, 1><<<(ROWS / 256) * (DFF / 128), 1024, 0, stream>>>(
      hb, w1t, b1, nullptr, gb, ROWS, DFF);
  // gemm2: [8192x4096]@[4096x1024] + resid -> out (f32). 256 blocks, 256x128, BK=64.
  gemm16v<DFF, 2><<<(ROWS / 256) * (DMODEL / 128), 1024, 0, stream>>>(
      gb, w2t, b2, out, out, ROWS, DMODEL);
}

// Round 12
// 210.781 us; speedup vs baseline: 1.0635x; 1.0627x over previous
//
#include <hip/hip_runtime.h>
#include <cstdint>
#include <cstddef>

// Problem: x += ssm_scan(rmsnorm(x,s1)); out = x + gelu(rmsnorm(x,s2)@w1+b1)@w2+b2
// B=4 L=2048 D=1024 N=16 DFF=4096, f32 in/out. bf16 MFMA GEMMs, 16 waves/block.

#define BATCH 4
#define SEQLEN 2048
#define DMODEL 1024
#define NSTATE 16
#define DFF 4096
#define NCH 32     // chunks over L
#define LCH 64     // SEQLEN / NCH

typedef unsigned short ushort_t;
typedef __attribute__((ext_vector_type(8))) short short8;
typedef __attribute__((ext_vector_type(4))) float f32x4;

__device__ __forceinline__ ushort_t f2bf(float f) {
  uint32_t u = __builtin_bit_cast(uint32_t, f);
  uint32_t r = (u + 0x7FFFu + ((u >> 16) & 1u)) >> 16;
  return (ushort_t)r;
}

// ---------------- coefficient precompute ----------------
__global__ void coef_kernel(const float* __restrict__ A_ssm, const float* __restrict__ B_ssm,
                            const float* __restrict__ C_ssm,
                            float* __restrict__ dA_t, float* __restrict__ dBz_t,
                            float* __restrict__ dAc_t, float* __restrict__ Ct) {
  int d = blockIdx.x * 256 + threadIdx.x;
  if (d >= DMODEL) return;
  const float l0 = -6.907755278982137f;       // log(0.001)
  const float ld = 0.30701134573253947f;      // log(100)/15
  for (int n = 0; n < NSTATE; n++) {
    float dt = expf(l0 + (float)n * ld);
    float a  = A_ssm[d * NSTATE + n];
    float ea = expf(a);
    float da = expf(-ea * dt);
    float dbz = B_ssm[d * NSTATE + n] * (1.f - da) / ea;
    float dac = expf(-ea * dt * (float)LCH);
    dA_t [n * DMODEL + d] = da;
    dBz_t[n * DMODEL + d] = dbz;
    dAc_t[n * DMODEL + d] = dac;
    Ct   [n * DMODEL + d] = C_ssm[d * NSTATE + n];
  }
}

// ---------------- transpose f32 [R][C] -> bf16 [C][R] ----------------
__global__ void transpose_to_bf16(const float* __restrict__ src, ushort_t* __restrict__ dst,
                                  int R, int C) {
  __shared__ float tile[32][33];
  int bx = blockIdx.x * 32, by = blockIdx.y * 32;
  int tx = threadIdx.x, ty = threadIdx.y;
  #pragma unroll
  for (int i = 0; i < 4; i++) {
    int r = by + ty + i * 8;
    tile[ty + i * 8][tx] = src[(size_t)r * C + bx + tx];
  }
  __syncthreads();
  #pragma unroll
  for (int i = 0; i < 4; i++) {
    int c = bx + ty + i * 8;
    dst[(size_t)c * R + by + tx] = f2bf(tile[tx][ty + i * 8]);
  }
}

// ---------------- rmsnorm pass 1: rrms per row ----------------
__global__ void rms1_kernel(const float* __restrict__ x, float* __restrict__ rrms) {
  int row = blockIdx.x * 4 + (threadIdx.x >> 6);
  int lane = threadIdx.x & 63;
  const float4* p = (const float4*)(x + (size_t)row * DMODEL);
  float s = 0.f;
  #pragma unroll
  for (int w = 0; w < 4; w++) {
    float4 v = p[w * 64 + lane];
    s += v.x * v.x + v.y * v.y + v.z * v.z + v.w * v.w;
  }
  #pragma unroll
  for (int off = 32; off; off >>= 1) s += __shfl_xor(s, off, 64);
  if (lane == 0) rrms[row] = rsqrtf(s * (1.f / DMODEL) + 1e-6f);
}

// ---------------- scan pass1: per-chunk local final states ----------------
__global__ void scan_pass1(const float* __restrict__ x, const float* __restrict__ rrms,
                           const float* __restrict__ scale1,
                           const float* __restrict__ dA_t, const float* __restrict__ dBz_t,
                           float* __restrict__ s_fin) {
  int d = blockIdx.x * 256 + threadIdx.x;
  int b = blockIdx.y, c = blockIdx.z;
  float dA[NSTATE], dBz[NSTATE], s[NSTATE];
  #pragma unroll
  for (int n = 0; n < NSTATE; n++) {
    dA[n] = dA_t[n * DMODEL + d];
    dBz[n] = dBz_t[n * DMODEL + d];
    s[n] = 0.f;
  }
  float sc1 = scale1[d];
  const float* xp = x + ((size_t)b * SEQLEN + (size_t)c * LCH) * DMODEL + d;
  const float* rp = rrms + b * SEQLEN + c * LCH;
  for (int t = 0; t < LCH; t++) {
    float u = xp[(size_t)t * DMODEL] * rp[t] * sc1;
    #pragma unroll
    for (int n = 0; n < NSTATE; n++) s[n] = fmaf(s[n], dA[n], u * dBz[n]);
  }
  #pragma unroll
  for (int n = 0; n < NSTATE; n++)
    s_fin[(((size_t)n * BATCH + b) * NCH + c) * DMODEL + d] = s[n];
}

// ---------------- scan pass2: serial chunk-carry combine ----------------
__global__ void scan_pass2(const float* __restrict__ s_fin, const float* __restrict__ dAc_t,
                           float* __restrict__ s_in) {
  int idx = blockIdx.x * 256 + threadIdx.x;  // BATCH*DMODEL*NSTATE = 65536
  int d = idx & (DMODEL - 1);
  int b = (idx >> 10) & (BATCH - 1);
  int n = idx >> 12;
  float dc = dAc_t[n * DMODEL + d];
  float s = 0.f;
  for (int c = 0; c < NCH; c++) {
    size_t o = (((size_t)n * BATCH + b) * NCH + c) * DMODEL + d;
    s_in[o] = s;
    s = s_fin[o] + dc * s;
  }
}

// ---------------- scan pass3: full scan with carry-in, write x2 = x + y + u*D ----------------
__global__ void scan_pass3(const float* __restrict__ x, const float* __restrict__ rrms,
                           const float* __restrict__ scale1,
                           const float* __restrict__ dA_t, const float* __restrict__ dBz_t,
                           const float* __restrict__ Ct, const float* __restrict__ Dv,
                           const float* __restrict__ s_in, float* __restrict__ out) {
  int d = blockIdx.x * 256 + threadIdx.x;
  int b = blockIdx.y, c = blockIdx.z;
  float dA[NSTATE], dBz[NSTATE], Cc[NSTATE], s[NSTATE];
  #pragma unroll
  for (int n = 0; n < NSTATE; n++) {
    dA[n] = dA_t[n * DMODEL + d];
    dBz[n] = dBz_t[n * DMODEL + d];
    Cc[n] = Ct[n * DMODEL + d];
    s[n] = s_in[(((size_t)n * BATCH + b) * NCH + c) * DMODEL + d];
  }
  float sc1 = scale1[d], Dd = Dv[d];
  const float* xp = x + ((size_t)b * SEQLEN + (size_t)c * LCH) * DMODEL + d;
  const float* rp = rrms + b * SEQLEN + c * LCH;
  float* op = out + ((size_t)b * SEQLEN + (size_t)c * LCH) * DMODEL + d;
  for (int t = 0; t < LCH; t++) {
    float xv = xp[(size_t)t * DMODEL];
    float u = xv * rp[t] * sc1;
    float y = 0.f;
    #pragma unroll
    for (int n = 0; n < NSTATE; n++) {
      s[n] = fmaf(s[n], dA[n], u * dBz[n]);
      y = fmaf(Cc[n], s[n], y);
    }
    op[(size_t)t * DMODEL] = xv + y + u * Dd;
  }
}

// ---------------- rmsnorm2: x2 -> bf16 normalized ----------------
__global__ void rms2_kernel(const float* __restrict__ x2, const float* __restrict__ scale2,
                            ushort_t* __restrict__ hb) {
  int row = blockIdx.x * 4 + (threadIdx.x >> 6);
  int lane = threadIdx.x & 63;
  const float4* p = (const float4*)(x2 + (size_t)row * DMODEL);
  float4 v[4];
  float s = 0.f;
  #pragma unroll
  for (int w = 0; w < 4; w++) {
    v[w] = p[w * 64 + lane];
    s += v[w].x * v[w].x + v[w].y * v[w].y + v[w].z * v[w].z + v[w].w * v[w].w;
  }
  #pragma unroll
  for (int off = 32; off; off >>= 1) s += __shfl_xor(s, off, 64);
  float r = rsqrtf(s * (1.f / DMODEL) + 1e-6f);
  const float4* sc = (const float4*)scale2;
  #pragma unroll
  for (int w = 0; w < 4; w++) {
    float4 scv = sc[w * 64 + lane];
    ushort4 u;
    u.x = f2bf(v[w].x * r * scv.x);
    u.y = f2bf(v[w].y * r * scv.y);
    u.z = f2bf(v[w].z * r * scv.z);
    u.w = f2bf(v[w].w * r * scv.w);
    *(ushort4*)(hb + (size_t)row * DMODEL + (size_t)(w * 64 + lane) * 4) = u;
  }
}

template <int N>
__device__ __forceinline__ void fence_vm() {
  asm volatile("s_waitcnt vmcnt(%0)" :: "n"(N) : "memory");
}

__device__ __forceinline__ void bar() { asm volatile("s_barrier" ::: "memory"); }

__device__ __forceinline__ void gl2lds16(const ushort_t* g, ushort_t* l) {
  __builtin_amdgcn_global_load_lds(
      (const __attribute__((address_space(1))) unsigned int*)g,
      (__attribute__((address_space(3))) unsigned int*)l, 16, 0, 0);
}

// ========== gemm1: 256x256, BK=64, 2-slot (128 KB), 16 waves, wave tile 64x64 ==========
// LDS-read floor 1.5x lower than 64x32 wave (reads ~ WM+WN, FLOPs ~ WM*WN); BK=64 keeps
// sync amortization (r9's 64x64@BK=32 lost to sync frequency). 2-slot: stage(t+1) at
// tile TOP, fence<0> at tile END (~3000cy later) -> drain is latency-free. kk-split
// fragment reuse caps live frags at 32 VGPR (acc 64) -> 4 waves/SIMD.
template <int K>
__global__ __launch_bounds__(1024, 4) void gemm_w64(const ushort_t* __restrict__ A,
                                                    const ushort_t* __restrict__ B,
                                                    const float* __restrict__ bias,
                                                    ushort_t* __restrict__ outp,
                                                    int M, int N) {
  constexpr int SLOT = 32768;               // elems: A 256x64 + B 256x64 (64 KB)
  constexpr int NT = K / 64;
  __shared__ __align__(16) ushort_t lds[2 * SLOT];   // 128 KB

  const int tid = threadIdx.x;
  const int wave = tid >> 6, lane = tid & 63;
  const int wr = wave >> 2, wc = wave & 3;

  const int nwg = gridDim.x, cpx = nwg >> 3, bid = blockIdx.x;
  const int wg = (bid & 7) * cpx + (bid >> 3);
  const int nbn = N / 256;
  const int m0 = (wg / nbn) * 256, n0 = (wg % nbn) * 256;

  // staging: row = tid>>3 (0..127, +128 for second load), chunk = tid&7 (BK=64 swizzle)
  const int scol = 8 * ((tid & 7) ^ ((tid >> 3) & 7));
  const int wo = wave * 512;
  const ushort_t* aStg = A + (size_t)(m0 + (tid >> 3)) * K + scol;
  const ushort_t* aStg2 = aStg + (size_t)128 * K;
  const ushort_t* bStg = B + (size_t)(n0 + (tid >> 3)) * K + scol;
  const ushort_t* bStg2 = bStg + (size_t)128 * K;

  f32x4 acc[4][4] = {};

  // prologue: stage tile 0 into slot 0
  {
    ushort_t* d = lds + wo;
    gl2lds16(aStg,  d);
    gl2lds16(aStg2, d + 8192);
    gl2lds16(bStg,  d + 16384);
    gl2lds16(bStg2, d + 24576);
    aStg += 64; aStg2 += 64; bStg += 64; bStg2 += 64;
  }
  fence_vm<0>(); bar();

  const int rl = lane & 15, c4 = lane >> 4;
  const int sw0 = (c4 ^ (rl & 7)) * 8;           // kk=0 read swizzle (BK=64 pattern)
  const int sw1 = ((4 | c4) ^ (rl & 7)) * 8;     // kk=1
  const int aOff = (wr * 64 + rl) * 64;          // thread A base (elems)
  const int bOff = 16384 + (wc * 64 + rl) * 64;  // thread B base (elems)

  const ushort_t* rSlot = lds;
  ushort_t*       wSlot = lds + SLOT;

  for (int t = 0; t < NT; ++t) {
    if (t + 1 < NT) {                       // stage t+1 at TOP (hides under this tile)
      gl2lds16(aStg,  wSlot + wo);
      gl2lds16(aStg2, wSlot + 8192 + wo);
      gl2lds16(bStg,  wSlot + 16384 + wo);
      gl2lds16(bStg2, wSlot + 24576 + wo);
      aStg += 64; aStg2 += 64; bStg += 64; bStg2 += 64;
    }

    const ushort_t* ra0 = rSlot + aOff + sw0;
    const ushort_t* ra1 = rSlot + aOff + sw1;
    const ushort_t* rb0 = rSlot + bOff + sw0;
    const ushort_t* rb1 = rSlot + bOff + sw1;

    {   // kk = 0
      short8 af[4], bf[4];
      #pragma unroll
      for (int m = 0; m < 4; m++) af[m] = *(const short8*)(ra0 + m * 1024);
      #pragma unroll
      for (int n = 0; n < 4; n++) bf[n] = *(const short8*)(rb0 + n * 1024);
      __builtin_amdgcn_s_setprio(1);
      #pragma unroll
      for (int m = 0; m < 4; m++)
        #pragma unroll
        for (int n = 0; n < 4; n++)
          acc[m][n] = __builtin_amdgcn_mfma_f32_16x16x32_bf16(af[m], bf[n], acc[m][n], 0, 0, 0);
      __builtin_amdgcn_s_setprio(0);
    }
    {   // kk = 1 (reuses fragment registers)
      short8 af[4], bf[4];
      #pragma unroll
      for (int m = 0; m < 4; m++) af[m] = *(const short8*)(ra1 + m * 1024);
      #pragma unroll
      for (int n = 0; n < 4; n++) bf[n] = *(const short8*)(rb1 + n * 1024);
      __builtin_amdgcn_s_setprio(1);
      #pragma unroll
      for (int m = 0; m < 4; m++)
        #pragma unroll
        for (int n = 0; n < 4; n++)
          acc[m][n] = __builtin_amdgcn_mfma_f32_16x16x32_bf16(af[m], bf[n], acc[m][n], 0, 0, 0);
      __builtin_amdgcn_s_setprio(0);
    }

    if (t + 1 < NT) { fence_vm<0>(); bar(); }
    const ushort_t* tmp = rSlot; rSlot = wSlot; wSlot = (ushort_t*)tmp;
  }

  // epilogue: gelu via sigmoid approx -> bf16
  const int colb = n0 + wc * 64 + rl;
  const int rowb = m0 + wr * 64 + c4 * 4;
  #pragma unroll
  for (int n = 0; n < 4; n++) {
    int col = colb + n * 16;
    float bs = bias[col];
    #pragma unroll
    for (int m = 0; m < 4; m++) {
      int row = rowb + m * 16;
      #pragma unroll
      for (int j = 0; j < 4; j++) {
        float v = acc[m][n][j] + bs;
        float g = v / (1.f + __expf(-1.702f * v));
        outp[(size_t)(row + j) * N + col] = f2bf(g);
      }
    }
  }
}

// ========== gemm2: r11 structure unchanged (256x128, BK=64, 3-slot, wave 64x32) ==========
template <int K, int MODE>
__global__ __launch_bounds__(1024, 4) void gemm16v(const ushort_t* __restrict__ A,
                                                   const ushort_t* __restrict__ B,
                                                   const float* __restrict__ bias,
                                                   const float* __restrict__ resid,
                                                   void* __restrict__ outp,
                                                   int M, int N) {
  constexpr int TILEA = 16384;              // A: 256x64 elems
  constexpr int SLOT  = TILEA + 8192;       // + B: 128x64
  constexpr int NT = K / 64;
  __shared__ __align__(16) ushort_t lds[3 * SLOT];   // 144 KB

  const int tid = threadIdx.x;
  const int wave = tid >> 6, lane = tid & 63;
  const int wr = wave >> 2, wc = wave & 3;

  const int nwg = gridDim.x, cpx = nwg >> 3, bid = blockIdx.x;
  const int wg = (bid & 7) * cpx + (bid >> 3);
  const int nbn = N / 128;
  const int m0 = (wg / nbn) * 256, n0 = (wg % nbn) * 128;

  const int scol = 8 * ((tid & 7) ^ ((tid >> 3) & 7));
  const int wo = wave * 512;

  const ushort_t* aStgLo = A + (size_t)(m0 + (tid >> 3)) * K + scol;
  const ushort_t* aStgHi = aStgLo + (size_t)128 * K;
  const ushort_t* bStg   = B + (size_t)(n0 + (tid >> 3)) * K + scol;

  f32x4 acc[4][2] = {};

  {
    ushort_t* s0p = lds;
    gl2lds16(aStgLo, s0p + wo);
    gl2lds16(aStgHi, s0p + 8192 + wo);
    gl2lds16(bStg,   s0p + TILEA + wo);
    ushort_t* s1p = lds + SLOT;
    gl2lds16(aStgLo + 64, s1p + wo);
    gl2lds16(aStgHi + 64, s1p + 8192 + wo);
    gl2lds16(bStg   + 64, s1p + TILEA + wo);
    aStgLo += 128; aStgHi += 128; bStg += 128;
  }
  fence_vm<3>(); bar();

  const int rl = lane & 15, c4 = lane >> 4;
  const int sw0 = (c4 ^ (rl & 7)) * 8;
  const int sw1 = ((4 | c4) ^ (rl & 7)) * 8;
  const int aOff = (wr * 64 + rl) * 64;
  const int bOff = TILEA + (wc * 32 + rl) * 64;

  const ushort_t* rSlot = lds;
  ushort_t*       wSlot = lds + 2 * SLOT;

  for (int t = 0; t < NT; ++t) {
    const ushort_t* ra0 = rSlot + aOff + sw0;
    const ushort_t* ra1 = rSlot + aOff + sw1;
    const ushort_t* rb0 = rSlot + bOff + sw0;
    const ushort_t* rb1 = rSlot + bOff + sw1;

    short8 af[2][4], bf[2][2];
    #pragma unroll
    for (int m = 0; m < 4; m++) {
      af[0][m] = *(const short8*)(ra0 + m * 1024);
      af[1][m] = *(const short8*)(ra1 + m * 1024);
    }
    #pragma unroll
    for (int n = 0; n < 2; n++) {
      bf[0][n] = *(const short8*)(rb0 + n * 1024);
      bf[1][n] = *(const short8*)(rb1 + n * 1024);
    }

    if (t + 2 < NT) {
      gl2lds16(aStgLo, wSlot + wo);
      gl2lds16(aStgHi, wSlot + 8192 + wo);
      gl2lds16(bStg,   wSlot + TILEA + wo);
      aStgLo += 64; aStgHi += 64; bStg += 64;
    }

    __builtin_amdgcn_s_setprio(1);
    #pragma unroll
    for (int kk = 0; kk < 2; kk++)
      #pragma unroll
      for (int m = 0; m < 4; m++)
        #pragma unroll
        for (int n = 0; n < 2; n++)
          acc[m][n] = __builtin_amdgcn_mfma_f32_16x16x32_bf16(af[kk][m], bf[kk][n],
                                                              acc[m][n], 0, 0, 0);
    __builtin_amdgcn_s_setprio(0);

    if (t + 2 < NT) fence_vm<3>();
    else            fence_vm<0>();
    bar();

    const ushort_t* rn = rSlot + SLOT;
    rSlot = (rn == lds + 3 * SLOT) ? lds : rn;
    ushort_t* wn = wSlot + SLOT;
    wSlot = (wn == lds + 3 * SLOT) ? lds : wn;
  }

  const int colb = n0 + wc * 32 + rl;
  const int rowb = m0 + wr * 64 + c4 * 4;
  #pragma unroll
  for (int n = 0; n < 2; n++) {
    int col = colb + n * 16;
    float bs = bias[col];
    #pragma unroll
    for (int m = 0; m < 4; m++) {
      int row = rowb + m * 16;
      #pragma unroll
      for (int j = 0; j < 4; j++) {
        float v = acc[m][n][j] + bs;
        size_t o = (size_t)(row + j) * N + col;
        if (MODE == 1) {
          float g = v / (1.f + __expf(-1.702f * v));
          ((ushort_t*)outp)[o] = f2bf(g);
        } else {
          ((float*)outp)[o] = resid[o] + v;
        }
      }
    }
  }
}

// ---------------- launch ----------------
extern "C" void kernel_launch(void* const* d_in, const int* in_sizes, int n_in,
                              void* d_out, int out_size, void* d_ws, size_t ws_size,
                              hipStream_t stream) {
  (void)in_sizes; (void)n_in; (void)out_size; (void)ws_size;
  const float* x      = (const float*)d_in[0];
  const float* A_ssm  = (const float*)d_in[1];
  const float* B_ssm  = (const float*)d_in[2];
  const float* C_ssm  = (const float*)d_in[3];
  const float* D_ssm  = (const float*)d_in[4];
  const float* scale1 = (const float*)d_in[5];
  const float* scale2 = (const float*)d_in[6];
  const float* w1     = (const float*)d_in[7];
  const float* b1     = (const float*)d_in[8];
  const float* w2     = (const float*)d_in[9];
  const float* b2     = (const float*)d_in[10];
  float* out = (float*)d_out;

  char* ws = (char*)d_ws;
  float*    rrms  = (float*)(ws + 0);                         // 32 KB
  float*    dA_t  = (float*)(ws + 32768);                     // 64 KB
  float*    dBz_t = (float*)(ws + 98304);                     // 64 KB
  float*    dAc_t = (float*)(ws + 163840);                    // 64 KB
  float*    Ct    = (float*)(ws + 229376);                    // 64 KB
  float*    s_fin = (float*)(ws + 294912);                    // 8 MB
  float*    s_in  = (float*)(ws + 8683520);                   // 8 MB
  ushort_t* hb    = (ushort_t*)(ws + 17072128);               // 16 MB
  ushort_t* w1t   = (ushort_t*)(ws + 33849344);               // 8 MB
  ushort_t* w2t   = (ushort_t*)(ws + 42237952);               // 8 MB
  ushort_t* gb    = (ushort_t*)(ws + 50626560);               // 64 MB

  const int ROWS = BATCH * SEQLEN;  // 8192

  coef_kernel<<<DMODEL / 256, 256, 0, stream>>>(A_ssm, B_ssm, C_ssm, dA_t, dBz_t, dAc_t, Ct);
  transpose_to_bf16<<<dim3(DFF / 32, DMODEL / 32), dim3(32, 8), 0, stream>>>(w1, w1t, DMODEL, DFF);
  transpose_to_bf16<<<dim3(DMODEL / 32, DFF / 32), dim3(32, 8), 0, stream>>>(w2, w2t, DFF, DMODEL);
  rms1_kernel<<<ROWS / 4, 256, 0, stream>>>(x, rrms);
  scan_pass1<<<dim3(DMODEL / 256, BATCH, NCH), 256, 0, stream>>>(x, rrms, scale1, dA_t, dBz_t, s_fin);
  scan_pass2<<<(BATCH * DMODEL * NSTATE) / 256, 256, 0, stream>>>(s_fin, dAc_t, s_in);
  scan_pass3<<<dim3(DMODEL / 256, BATCH, NCH), 256, 0, stream>>>(x, rrms, scale1, dA_t, dBz_t, Ct,
                                                                 D_ssm, s_in, out);
  rms2_kernel<<<ROWS / 4, 256, 0, stream>>>(out, scale2, hb);

  // gemm1: [8192x1024]@[1024x4096] -> gelu -> gb (bf16). 512 blocks, 256x256, BK=64.
  gemm_w64<DMODEL><<<(ROWS / 256) * (DFF / 256), 1024, 0, stream>>>(
      hb, w1t, b1, gb, ROWS, DFF);
  // gemm2: [8192x4096]@[4096x1024] + resid -> out (f32). 256 blocks, 256x128, BK=64.
  gemm16v<DFF, 2><<<(ROWS / 256) * (DMODEL / 128), 1024, 0, stream>>>(
      gb, w2t, b2, out, out, ROWS, DMODEL);
}